// Round 9
// baseline (2079.383 us; speedup 1.0000x reference)
//
#include <hip/hip_runtime.h>
#include <hip/hip_bf16.h>
#include <math.h>

// GGNN: N=50000 nodes, E=400000 edges, G=64 graphs, IN=64, OUT=128, 4 etypes, 8 steps.
// R9: barrier-free k_gpre. R8 showed FETCH 131->38 MB (XCD swizzle works) but time
//   ~flat: the 5-chunk stage->barrier->mfma pipeline is latency-bound, not byte-bound.
//   Fix: no LDS at all. B fragments read straight from Wbig (640 KB, L2-resident per
//   XCD), A fragments straight from x (tile L2-shared via swizzle). Zero barriers ->
//   independent streaming waves, VGPR-limited occupancy.
//   Algebra (R7): s = per-etype neighbor sums; x=[s|hb]; P = x.Wbig^T + bias + deg4-fix.
//   Step: k_agg4 ; k_gpre ; k_gru2.

#define NN 50000
#define NE 400000
#define NG 64
#define IND 64
#define OD 128
#define LDX 640   // x row (halfs): 0..511 = s (4 etype sums), 512..639 = hb
#define LDP 512   // P row (halfs): pr | pz | pin | phn
#define RC 8      // readout chunks per graph
#define NT 391    // row tiles (128 rows each)

typedef _Float16 f16x8 __attribute__((ext_vector_type(8)));
typedef _Float16 f16x4 __attribute__((ext_vector_type(4)));
typedef float f32x4 __attribute__((ext_vector_type(4)));

__device__ inline unsigned short f2h(float x) {
    _Float16 hv = (_Float16)x;
    unsigned short u;
    __builtin_memcpy(&u, &hv, 2);
    return u;
}
__device__ inline float sigf(float x) { return 1.f / (1.f + __expf(-x)); }

// ---------------- init h = [node_features | 0] (fp32 + fp16 shadow in x) --------------
__global__ void k_init_h(const float* __restrict__ nf, float* __restrict__ h,
                         unsigned short* __restrict__ x) {
    int i = blockIdx.x * 256 + threadIdx.x;
    if (i >= NN * OD) return;
    int n = i >> 7, d = i & 127;
    float v = (d < IND) ? nf[n * IND + d] : 0.f;
    h[i] = v;
    x[(size_t)n * LDX + 512 + d] = f2h(v);
}

// ---------------- weight prep ----------------
// Wbig[512][640] fp16:
//  rows   0..127 (pr):  cols 0..511 = Wf_r = W_ih[r] . Wcat ; cols 512..639 = W_hh[r]
//  rows 128..255 (pz):  Wf_z | W_hh[z]
//  rows 256..383 (pin): Wf_n | 0
//  rows 384..511 (phn): 0    | W_hh[n]
__global__ void k_wbig(const float* __restrict__ Ws, const float* __restrict__ W_ih,
                       const float* __restrict__ W_hh, unsigned short* __restrict__ Wbig) {
    int o2 = blockIdx.x;   // 0..511
    for (int c = threadIdx.x; c < LDX; c += 256) {
        float v = 0.f;
        if (c < 512) {
            if (o2 < 384) {
                int t = c >> 7, k = c & 127;
                const float* wi = W_ih + (size_t)o2 * 128;
                const float* ws = Ws + (size_t)t * 16384 + k;
                float acc = 0.f;
                for (int o = 0; o < 128; ++o) acc += wi[o] * ws[(size_t)o * 128];
                v = acc;
            }
        } else {
            int k = c - 512;
            if (o2 < 256)      v = W_hh[(size_t)o2 * 128 + k];
            else if (o2 >= 384) v = W_hh[(size_t)(o2 - 384 + 256) * 128 + k];
        }
        Wbig[(size_t)o2 * LDX + c] = f2h(v);
    }
}

// bias512[o2] and dbv[o2][t] = (W_ih[gate] . bs[t])[o2&127]  (0 for phn rows)
__global__ void k_wbias(const float* __restrict__ W_ih, const float* __restrict__ bs,
                        const float* __restrict__ b_ih, const float* __restrict__ b_hh,
                        float* __restrict__ bias512, float* __restrict__ dbv) {
    int o2 = threadIdx.x;   // 512 threads
    float b;
    if (o2 < 256)      b = b_ih[o2] + b_hh[o2];          // pr, pz
    else if (o2 < 384) b = b_ih[o2];                     // pin
    else               b = b_hh[o2 - 384 + 256];         // phn
    bias512[o2] = b;
    for (int t = 0; t < 4; ++t) {
        float acc = 0.f;
        if (o2 < 384) {
            const float* wi = W_ih + (size_t)o2 * 128;
            const float* bt = bs + t * 128;
            for (int k = 0; k < 128; ++k) acc += wi[k] * bt[k];
        }
        dbv[o2 * 4 + t] = acc;
    }
}

// ---------------- edge CSR build (by dst) ----------------
__global__ void k_count4(const int* __restrict__ dst, const int* __restrict__ et,
                         int* __restrict__ deg, int* __restrict__ deg4) {
    int e = blockIdx.x * 256 + threadIdx.x;
    if (e < NE) {
        int d = dst[e];
        atomicAdd(&deg[d], 1);
        atomicAdd(&deg4[d * 4 + et[e]], 1);
    }
}

__global__ void k_scan1(const int* __restrict__ deg, int* __restrict__ rowp,
                        int* __restrict__ bsum) {
    __shared__ int buf[1024];
    int tid = threadIdx.x;
    int i = blockIdx.x * 1024 + tid;
    int v = (i < NN) ? deg[i] : 0;
    buf[tid] = v;
    __syncthreads();
    for (int off = 1; off < 1024; off <<= 1) {
        int t = (tid >= off) ? buf[tid - off] : 0;
        __syncthreads();
        buf[tid] += t;
        __syncthreads();
    }
    if (i < NN) rowp[i + 1] = buf[tid];
    if (tid == 1023) bsum[blockIdx.x] = buf[tid];
}

__global__ void k_scan2(int* __restrict__ bsum, int nb) {
    __shared__ int buf[64];
    int tid = threadIdx.x;
    int v = (tid < nb) ? bsum[tid] : 0;
    buf[tid] = v;
    __syncthreads();
    for (int off = 1; off < 64; off <<= 1) {
        int t = (tid >= off) ? buf[tid - off] : 0;
        __syncthreads();
        buf[tid] += t;
        __syncthreads();
    }
    if (tid < nb) bsum[tid] = buf[tid] - v;   // exclusive
}

__global__ void k_scan3(const int* __restrict__ deg, const int* __restrict__ bsum,
                        int* __restrict__ rowp, int* __restrict__ cursor) {
    int i = blockIdx.x * 256 + threadIdx.x;
    if (i >= NN) return;
    int incl = rowp[i + 1] + bsum[i >> 10];
    rowp[i + 1] = incl;
    cursor[i] = incl - deg[i];
    if (i == 0) rowp[0] = 0;
}

__global__ void k_fill(const int* __restrict__ src, const int* __restrict__ dst,
                       const int* __restrict__ et, int* __restrict__ cursor,
                       int* __restrict__ epack) {
    int e = blockIdx.x * 256 + threadIdx.x;
    if (e < NE) {
        int pos = atomicAdd(&cursor[dst[e]], 1);
        epack[pos] = src[e] * 4 + et[e];
    }
}

// ---------------- graph CSR build (by graph id), for readout ----------------
__global__ void k_gcount(const int* __restrict__ gid, int* __restrict__ gdeg) {
    __shared__ int c[NG];
    int tid = threadIdx.x;
    if (tid < NG) c[tid] = 0;
    __syncthreads();
    int n = blockIdx.x * 1024 + tid;
    if (n < NN) atomicAdd(&c[gid[n]], 1);
    __syncthreads();
    if (tid < NG && c[tid] > 0) atomicAdd(&gdeg[tid], c[tid]);
}

__global__ void k_gscan(const int* __restrict__ gdeg, int* __restrict__ growp,
                        int* __restrict__ gcur) {
    __shared__ int buf[NG];
    int tid = threadIdx.x;
    int v = gdeg[tid];
    buf[tid] = v;
    __syncthreads();
    for (int off = 1; off < NG; off <<= 1) {
        int t = (tid >= off) ? buf[tid - off] : 0;
        __syncthreads();
        buf[tid] += t;
        __syncthreads();
    }
    growp[tid + 1] = buf[tid];
    gcur[tid] = buf[tid] - v;
    if (tid == 0) growp[0] = 0;
}

__global__ void k_gfill(const int* __restrict__ gid, int* __restrict__ gcur,
                        int* __restrict__ nlist) {
    __shared__ int lcnt[NG];
    __shared__ int lbase[NG];
    int tid = threadIdx.x;
    if (tid < NG) lcnt[tid] = 0;
    __syncthreads();
    int n = blockIdx.x * 1024 + tid;
    int g = -1, rank = 0;
    if (n < NN) { g = gid[n]; rank = atomicAdd(&lcnt[g], 1); }
    __syncthreads();
    if (tid < NG && lcnt[tid] > 0) lbase[tid] = atomicAdd(&gcur[tid], lcnt[tid]);
    __syncthreads();
    if (n < NN) nlist[lbase[g] + rank] = n;
}

// ---------------- per-etype segment sum: s[n][t*128+d] = sum hb[src] over etype-t edges
__global__ void k_agg4(unsigned short* x, const int* __restrict__ rowp,
                       const int* __restrict__ epack) {
    int wv = (blockIdx.x * 256 + threadIdx.x) >> 6;
    int lane = threadIdx.x & 63;
    int n = wv * 2 + (lane >> 5);
    if (n >= NN) return;
    int d4 = (lane & 31) * 4;
    int beg = rowp[n], end = rowp[n + 1];
    float acc[4][4];
#pragma unroll
    for (int t = 0; t < 4; ++t)
#pragma unroll
        for (int j = 0; j < 4; ++j) acc[t][j] = 0.f;
    for (int i = beg; i < end; ++i) {
        int p = epack[i];
        int t = p & 3;
        f16x4 v = *(const f16x4*)&x[(size_t)(p >> 2) * LDX + 512 + d4];
        float v0 = (float)v[0], v1 = (float)v[1], v2 = (float)v[2], v3 = (float)v[3];
        if (t == 0)      { acc[0][0] += v0; acc[0][1] += v1; acc[0][2] += v2; acc[0][3] += v3; }
        else if (t == 1) { acc[1][0] += v0; acc[1][1] += v1; acc[1][2] += v2; acc[1][3] += v3; }
        else if (t == 2) { acc[2][0] += v0; acc[2][1] += v1; acc[2][2] += v2; acc[2][3] += v3; }
        else             { acc[3][0] += v0; acc[3][1] += v1; acc[3][2] += v2; acc[3][3] += v3; }
    }
#pragma unroll
    for (int t = 0; t < 4; ++t) {
        f16x4 r;
        r[0] = (_Float16)acc[t][0]; r[1] = (_Float16)acc[t][1];
        r[2] = (_Float16)acc[t][2]; r[3] = (_Float16)acc[t][3];
        *(f16x4*)&x[(size_t)n * LDX + t * 128 + d4] = r;
    }
}

// ---------------- gates-pre GEMM: P[n, g*128+o] = x[n,:].Wbig[g*128+o,:] + bias -------
// Grid: 1568 blocks, XCD-swizzled: xcd=b&7, j=b>>3, group=j&3, tile=(j>>2)*8+xcd.
// Barrier-free: no LDS. A fragments direct from x (tile L2-shared across the 4 group
// blocks on this XCD); B fragments direct from Wbig (640 KB, L2-resident per XCD).
// MFMA layouts per guide §3: A[m=lane&15][k=quad*8+j], B[n=lane&15][k=quad*8+j],
// C/D[row=quad*4+reg][col=lane&15].
__global__ __launch_bounds__(256) void k_gpre(
    const unsigned short* __restrict__ x, const unsigned short* __restrict__ Wbig,
    const float* __restrict__ bias512, const float* __restrict__ dbv,
    const int* __restrict__ deg4, unsigned short* __restrict__ P) {
    const int b = blockIdx.x;
    const int xcd = b & 7, j = b >> 3;
    const int g = j & 3;
    const int tile = (j >> 2) * 8 + xcd;
    if (tile >= NT) return;
    const int m0 = tile * 128;
    const int tid = threadIdx.x;

    const int lane = tid & 63;
    const int w = tid >> 6;
    const int lr = lane & 15;
    const int q = lane >> 4;

    const int arow0 = m0 + w * 32 + lr;        // mt=0 A row for this lane
    const bool rok0 = arow0 < NN;
    const int arow1 = arow0 + 16;              // mt=1
    const bool rok1 = arow1 < NN;

    f16x8 zf;
#pragma unroll
    for (int jj = 0; jj < 8; ++jj) zf[jj] = (_Float16)0.f;

    f32x4 acc[2][8];
#pragma unroll
    for (int mt = 0; mt < 2; ++mt)
#pragma unroll
        for (int nt = 0; nt < 8; ++nt) acc[mt][nt] = (f32x4){0.f, 0.f, 0.f, 0.f};

    const unsigned short* wbase = Wbig + (size_t)(g * 128 + lr) * LDX + q * 8;

    for (int c = 0; c < 5; ++c) {
        // A fragments for this chunk (global; L2-hot after first group on this XCD)
        f16x8 af[2][4];
#pragma unroll
        for (int ks = 0; ks < 4; ++ks) {
            af[0][ks] = rok0 ? *(const f16x8*)&x[(size_t)arow0 * LDX + c * 128 + ks * 32 + q * 8] : zf;
            af[1][ks] = rok1 ? *(const f16x8*)&x[(size_t)arow1 * LDX + c * 128 + ks * 32 + q * 8] : zf;
        }
#pragma unroll
        for (int ks = 0; ks < 4; ++ks) {
            f16x8 bfr[8];
#pragma unroll
            for (int nt = 0; nt < 8; ++nt)
                bfr[nt] = *(const f16x8*)&wbase[(size_t)(nt * 16) * LDX + c * 128 + ks * 32];
#pragma unroll
            for (int mt = 0; mt < 2; ++mt)
#pragma unroll
                for (int nt = 0; nt < 8; ++nt)
                    acc[mt][nt] = __builtin_amdgcn_mfma_f32_16x16x32_f16(
                        af[mt][ks], bfr[nt], acc[mt][nt], 0, 0, 0);
        }
    }

#pragma unroll
    for (int mt = 0; mt < 2; ++mt) {
        int rowbase = m0 + w * 32 + mt * 16 + q * 4;
#pragma unroll
        for (int r = 0; r < 4; ++r) {
            int n = rowbase + r;
            if (n < NN) {
                int4 dg = *(const int4*)&deg4[n * 4];
                unsigned short* prow = P + (size_t)n * LDP + g * 128;
#pragma unroll
                for (int nt = 0; nt < 8; ++nt) {
                    int o = g * 128 + nt * 16 + lr;
                    float v = acc[mt][nt][r] + bias512[o]
                            + (float)dg.x * dbv[o * 4 + 0] + (float)dg.y * dbv[o * 4 + 1]
                            + (float)dg.z * dbv[o * 4 + 2] + (float)dg.w * dbv[o * 4 + 3];
                    prow[nt * 16 + lr] = f2h(v);
                }
            }
        }
    }
}

// ---------------- pointwise GRU: P=[pr|pz|pin|phn] -> h, hb (4 dims/thread) -----------
__global__ void k_gru2(const unsigned short* __restrict__ P, float* __restrict__ h,
                       unsigned short* x) {
    int i = blockIdx.x * 256 + threadIdx.x;
    if (i >= NN * 32) return;
    int n = i >> 5, d = (i & 31) * 4;
    const unsigned short* pr = P + (size_t)n * LDP;
    f16x4 vr = *(const f16x4*)&pr[d];
    f16x4 vz = *(const f16x4*)&pr[128 + d];
    f16x4 vi = *(const f16x4*)&pr[256 + d];
    f16x4 vh = *(const f16x4*)&pr[384 + d];
    float4 hv = *(const float4*)&h[(size_t)n * OD + d];
    float nh[4];
    float hvv[4] = {hv.x, hv.y, hv.z, hv.w};
#pragma unroll
    for (int jj = 0; jj < 4; ++jj) {
        float r = sigf((float)vr[jj]);
        float z = sigf((float)vz[jj]);
        float ng = tanhf((float)vi[jj] + r * (float)vh[jj]);
        nh[jj] = (1.f - z) * ng + z * hvv[jj];
    }
    *(float4*)&h[(size_t)n * OD + d] = make_float4(nh[0], nh[1], nh[2], nh[3]);
    f16x4 hb4;
    hb4[0] = (_Float16)nh[0]; hb4[1] = (_Float16)nh[1];
    hb4[2] = (_Float16)nh[2]; hb4[3] = (_Float16)nh[3];
    *(f16x4*)&x[(size_t)n * LDX + 512 + d] = hb4;
}

// ---------------- graph readout: register acc over graph-sorted node list --------------
__global__ void k_readout(const float* __restrict__ h, const float* __restrict__ nf,
                          const int* __restrict__ nlist, const int* __restrict__ growp,
                          float* __restrict__ partial) {
    int g = blockIdx.x >> 3, c = blockIdx.x & (RC - 1);
    int d = threadIdx.x;
    int s = growp[g], e = growp[g + 1], len = e - s;
    int i0 = s + (int)((long long)len * c / RC);
    int i1 = s + (int)((long long)len * (c + 1) / RC);
    float acc = 0.f;
    for (int i = i0; i < i1; ++i) {
        int n = nlist[i];
        acc += (d < OD) ? h[(size_t)n * OD + d] : nf[(size_t)n * IND + (d - OD)];
    }
    partial[(size_t)blockIdx.x * 192 + d] = acc;
}

__global__ void k_reduce(const float* __restrict__ partial, float* __restrict__ feats) {
    int i = blockIdx.x * 256 + threadIdx.x;
    if (i >= NG * 192) return;
    int g = i / 192, d = i % 192;
    float s = 0.f;
    for (int c = 0; c < RC; ++c) s += partial[(size_t)(g * RC + c) * 192 + d];
    feats[i] = s;
}

__global__ void k_final(const float* __restrict__ feats, const float* __restrict__ W_cls,
                        const float* __restrict__ b_cls, float* __restrict__ out) {
    int g = threadIdx.x;
    if (g >= NG) return;
    float acc = b_cls[0];
    for (int d = 0; d < 192; ++d) acc += feats[g * 192 + d] * W_cls[d];
    out[g] = 1.f / (1.f + __expf(-acc));
}

extern "C" void kernel_launch(void* const* d_in, const int* in_sizes, int n_in,
                              void* d_out, int out_size, void* d_ws, size_t ws_size,
                              hipStream_t stream) {
    const float* nf    = (const float*)d_in[0];
    const int*   src   = (const int*)d_in[1];
    const int*   dst   = (const int*)d_in[2];
    const int*   et    = (const int*)d_in[3];
    const int*   gid   = (const int*)d_in[4];
    const float* Ws    = (const float*)d_in[5];
    const float* bs    = (const float*)d_in[6];
    const float* W_ih  = (const float*)d_in[7];
    const float* W_hh  = (const float*)d_in[8];
    const float* b_ih  = (const float*)d_in[9];
    const float* b_hh  = (const float*)d_in[10];
    const float* W_cls = (const float*)d_in[11];
    const float* b_cls = (const float*)d_in[12];
    float* out = (float*)d_out;

    char* ws = (char*)d_ws;
    size_t off = 0;
    auto alloc = [&](size_t bytes) -> void* {
        off = (off + 255) & ~(size_t)255;
        void* p = ws + off;
        off += bytes;
        return p;
    };
    float*          h     = (float*)alloc((size_t)NN * OD * 4);            // 25.6 MB
    unsigned short* x     = (unsigned short*)alloc((size_t)NN * LDX * 2);  // 64 MB
    unsigned short* P     = (unsigned short*)alloc((size_t)NN * LDP * 2);  // 51.2 MB
    unsigned short* Wbig  = (unsigned short*)alloc((size_t)512 * LDX * 2); // 640 KB
    float* bias512 = (float*)alloc(512 * 4);
    float* dbv     = (float*)alloc(512 * 4 * 4);
    int*   deg    = (int*)alloc((size_t)NN * 4);
    int*   deg4   = (int*)alloc((size_t)NN * 4 * 4);
    int*   rowp   = (int*)alloc((size_t)(NN + 1) * 4);
    int*   cursor = (int*)alloc((size_t)NN * 4);
    int*   epack  = (int*)alloc((size_t)NE * 4);
    int*   bsum   = (int*)alloc(64 * 4);
    int*   gdeg   = (int*)alloc(NG * 4);
    int*   growp  = (int*)alloc((NG + 1) * 4);
    int*   gcur   = (int*)alloc(NG * 4);
    int*   nlist  = (int*)alloc((size_t)NN * 4);
    float* feats  = (float*)alloc((size_t)NG * 192 * 4);
    (void)ws_size; (void)in_sizes; (void)n_in; (void)out_size;

    // readout partials alias the (dead-by-then) P buffer: 512*192*4 = 393 KB << 51 MB
    float* partial = (float*)P;

    hipMemsetAsync(deg, 0, (size_t)NN * 4, stream);
    hipMemsetAsync(deg4, 0, (size_t)NN * 4 * 4, stream);
    hipMemsetAsync(gdeg, 0, NG * 4, stream);

    k_wbig<<<512, 256, 0, stream>>>(Ws, W_ih, W_hh, Wbig);
    k_wbias<<<1, 512, 0, stream>>>(W_ih, bs, b_ih, b_hh, bias512, dbv);

    k_init_h<<<(NN * OD + 255) / 256, 256, 0, stream>>>(nf, h, x);
    k_count4<<<(NE + 255) / 256, 256, 0, stream>>>(dst, et, deg, deg4);
    const int nb = (NN + 1023) / 1024;   // 49
    k_scan1<<<nb, 1024, 0, stream>>>(deg, rowp, bsum);
    k_scan2<<<1, 64, 0, stream>>>(bsum, nb);
    k_scan3<<<(NN + 255) / 256, 256, 0, stream>>>(deg, bsum, rowp, cursor);
    k_fill<<<(NE + 255) / 256, 256, 0, stream>>>(src, dst, et, cursor, epack);

    k_gcount<<<nb, 1024, 0, stream>>>(gid, gdeg);
    k_gscan<<<1, NG, 0, stream>>>(gdeg, growp, gcur);
    k_gfill<<<nb, 1024, 0, stream>>>(gid, gcur, nlist);

    const int aggblk = (NN * 32 + 255) / 256;   // 2 nodes per wave
    const int gpreblk = 8 * ((NT + 7) / 8) * 4; // 1568, XCD-swizzled
    for (int s = 0; s < 8; ++s) {
        k_agg4<<<aggblk, 256, 0, stream>>>(x, rowp, epack);
        k_gpre<<<gpreblk, 256, 0, stream>>>(x, Wbig, bias512, dbv, deg4, P);
        k_gru2<<<(NN * 32 + 255) / 256, 256, 0, stream>>>(P, h, x);
    }

    k_readout<<<NG * RC, 192, 0, stream>>>(h, nf, nlist, growp, partial);
    k_reduce<<<(NG * 192 + 255) / 256, 256, 0, stream>>>(partial, feats);
    k_final<<<1, 64, 0, stream>>>(feats, W_cls, b_cls, out);
}

// Round 10
// 1144.830 us; speedup vs baseline: 1.8163x; 1.8163x over previous
//
#include <hip/hip_runtime.h>
#include <hip/hip_bf16.h>
#include <math.h>

// GGNN: N=50000 nodes, E=400000 edges, G=64 graphs, IN=64, OUT=128, 4 etypes, 8 steps.
// R10: all step kernels in the PROVEN R5 GEMM shape (single K=128 LDS chunk, 2 barriers,
//   many short blocks) — R6/R8/R9 established that multi-chunk pipelines and LDS-free
//   global-B reads are 2-4x slower (latency-bound). Kept verified wins only:
//   - XCD swizzle (R8: FETCH 131->38 MB) so a tile's group-blocks share A-tiles in L2
//   - O = 4 etype groups only (51.2 MB), biases folded so aggregate carries deg*b_t
//   - P=[pr|pz|pin|phn] gate layout, each gate rounded ONCE from fp32 mfma sums
//   Step: k_gemm_a (hb -> O) ; k_aggregate (gather -> ab) ;
//         k_gemm_p ([ab,hb] -> P, <=2 proven stages per group) ; k_gru2 (P -> h,hb).

#define NN 50000
#define NE 400000
#define NG 64
#define IND 64
#define OD 128
#define LDO 512   // O row (halfs): Wh for etypes 0..3 (bias b_t included)
#define LDP 512   // P row (halfs): pr | pz | pin | phn
#define RC 8      // readout chunks per graph
#define NT 391    // row tiles (128 rows each)
#define SWGRID 1568  // 8 * ceil(391/8) * 4 swizzled blocks

typedef _Float16 f16x8 __attribute__((ext_vector_type(8)));
typedef _Float16 f16x4 __attribute__((ext_vector_type(4)));
typedef float f32x4 __attribute__((ext_vector_type(4)));

__device__ inline unsigned short f2h(float x) {
    _Float16 hv = (_Float16)x;
    unsigned short u;
    __builtin_memcpy(&u, &hv, 2);
    return u;
}
__device__ inline float sigf(float x) { return 1.f / (1.f + __expf(-x)); }

// ---------------- fp32 -> fp16 weight conversion (all 10 matrices, one kernel) --------
// wall layout: [Ws(4x16384) | W_ih(3x16384) | W_hh(3x16384)]
__global__ void k_cvt_all(const float* __restrict__ Ws, const float* __restrict__ W_ih,
                          const float* __restrict__ W_hh, unsigned short* __restrict__ wall) {
    int i = blockIdx.x * 256 + threadIdx.x;
    if (i >= 10 * 16384) return;
    float v;
    if (i < 4 * 16384) v = Ws[i];
    else if (i < 7 * 16384) v = W_ih[i - 4 * 16384];
    else v = W_hh[i - 7 * 16384];
    wall[i] = f2h(v);
}

// ---------------- init h = [node_features | 0] (fp32 + fp16 shadow) ----------------
__global__ void k_init_h(const float* __restrict__ nf, float* __restrict__ h,
                         unsigned short* __restrict__ hb) {
    int i = blockIdx.x * 256 + threadIdx.x;
    if (i >= NN * OD) return;
    int n = i >> 7, d = i & 127;
    float v = (d < IND) ? nf[n * IND + d] : 0.f;
    h[i] = v;
    hb[i] = f2h(v);
}

// ---------------- edge CSR build (by dst) ----------------
__global__ void k_count(const int* __restrict__ dst, int* __restrict__ deg) {
    int e = blockIdx.x * 256 + threadIdx.x;
    if (e < NE) atomicAdd(&deg[dst[e]], 1);
}

__global__ void k_scan1(const int* __restrict__ deg, int* __restrict__ rowp,
                        int* __restrict__ bsum) {
    __shared__ int buf[1024];
    int tid = threadIdx.x;
    int i = blockIdx.x * 1024 + tid;
    int v = (i < NN) ? deg[i] : 0;
    buf[tid] = v;
    __syncthreads();
    for (int off = 1; off < 1024; off <<= 1) {
        int t = (tid >= off) ? buf[tid - off] : 0;
        __syncthreads();
        buf[tid] += t;
        __syncthreads();
    }
    if (i < NN) rowp[i + 1] = buf[tid];
    if (tid == 1023) bsum[blockIdx.x] = buf[tid];
}

__global__ void k_scan2(int* __restrict__ bsum, int nb) {
    __shared__ int buf[64];
    int tid = threadIdx.x;
    int v = (tid < nb) ? bsum[tid] : 0;
    buf[tid] = v;
    __syncthreads();
    for (int off = 1; off < 64; off <<= 1) {
        int t = (tid >= off) ? buf[tid - off] : 0;
        __syncthreads();
        buf[tid] += t;
        __syncthreads();
    }
    if (tid < nb) bsum[tid] = buf[tid] - v;   // exclusive
}

__global__ void k_scan3(const int* __restrict__ deg, const int* __restrict__ bsum,
                        int* __restrict__ rowp, int* __restrict__ cursor) {
    int i = blockIdx.x * 256 + threadIdx.x;
    if (i >= NN) return;
    int incl = rowp[i + 1] + bsum[i >> 10];
    rowp[i + 1] = incl;
    cursor[i] = incl - deg[i];
    if (i == 0) rowp[0] = 0;
}

__global__ void k_fill(const int* __restrict__ src, const int* __restrict__ dst,
                       const int* __restrict__ et, int* __restrict__ cursor,
                       int* __restrict__ ebase) {
    int e = blockIdx.x * 256 + threadIdx.x;
    if (e < NE) {
        int pos = atomicAdd(&cursor[dst[e]], 1);
        ebase[pos] = src[e] * LDO + et[e] * 128;   // half-index of this edge's message row
    }
}

// ---------------- graph CSR build (by graph id), for readout ----------------
__global__ void k_gcount(const int* __restrict__ gid, int* __restrict__ gdeg) {
    __shared__ int c[NG];
    int tid = threadIdx.x;
    if (tid < NG) c[tid] = 0;
    __syncthreads();
    int n = blockIdx.x * 1024 + tid;
    if (n < NN) atomicAdd(&c[gid[n]], 1);
    __syncthreads();
    if (tid < NG && c[tid] > 0) atomicAdd(&gdeg[tid], c[tid]);
}

__global__ void k_gscan(const int* __restrict__ gdeg, int* __restrict__ growp,
                        int* __restrict__ gcur) {
    __shared__ int buf[NG];
    int tid = threadIdx.x;
    int v = gdeg[tid];
    buf[tid] = v;
    __syncthreads();
    for (int off = 1; off < NG; off <<= 1) {
        int t = (tid >= off) ? buf[tid - off] : 0;
        __syncthreads();
        buf[tid] += t;
        __syncthreads();
    }
    growp[tid + 1] = buf[tid];
    gcur[tid] = buf[tid] - v;
    if (tid == 0) growp[0] = 0;
}

__global__ void k_gfill(const int* __restrict__ gid, int* __restrict__ gcur,
                        int* __restrict__ nlist) {
    __shared__ int lcnt[NG];
    __shared__ int lbase[NG];
    int tid = threadIdx.x;
    if (tid < NG) lcnt[tid] = 0;
    __syncthreads();
    int n = blockIdx.x * 1024 + tid;
    int g = -1, rank = 0;
    if (n < NN) { g = gid[n]; rank = atomicAdd(&lcnt[g], 1); }
    __syncthreads();
    if (tid < NG && lcnt[tid] > 0) lbase[tid] = atomicAdd(&gcur[tid], lcnt[tid]);
    __syncthreads();
    if (n < NN) nlist[lbase[g] + rank] = n;
}

// ---------------- GEMM_A: O[m, t*128+o] = hb[m,:].Ws_t[o,:] + bs_t[o]  (fp16 out) -----
// Proven R5 shape: 128x128 tile, K=128 single LDS chunk, 2 barriers.
// XCD swizzle: xcd=b&7, j=b>>3, g=j&3, tile=(j>>2)*8+xcd -> a tile's 4 group blocks
// land on one XCD and share the hb A-tile in L2 (R8-verified).
// MFMA layouts (guide §3): A[m=lane&15][k=quad*8+j], B[n=lane&15][k=quad*8+j],
// C/D[row=quad*4+reg][col=lane&15].
__global__ __launch_bounds__(256) void k_gemm_a(
    const unsigned short* __restrict__ hb,
    const unsigned short* __restrict__ Wsb,   // 4 x 16384 fp16
    const float* __restrict__ bs,
    unsigned short* __restrict__ O) {
    __shared__ unsigned short As[128 * 136];
    __shared__ unsigned short Bs[128 * 136];

    const int b = blockIdx.x;
    const int xcd = b & 7, j = b >> 3;
    const int g = j & 3;
    const int tile = (j >> 2) * 8 + xcd;
    if (tile >= NT) return;
    const int m0 = tile * 128;
    const int tid = threadIdx.x;

    const unsigned short* W = Wsb + (size_t)g * 16384;
    const float* bias = bs + g * 128;

    const uint4* A4 = (const uint4*)hb;
    const uint4* W4 = (const uint4*)W;

#pragma unroll
    for (int i = tid; i < 2048; i += 256) {
        int row = i >> 4, qq = i & 15;
        int n = m0 + row;
        uint4 va = (n < NN) ? A4[(size_t)n * 16 + qq] : make_uint4(0u, 0u, 0u, 0u);
        *(uint4*)&As[row * 136 + qq * 8] = va;
        *(uint4*)&Bs[row * 136 + qq * 8] = W4[(size_t)row * 16 + qq];
    }
    __syncthreads();

    const int lane = tid & 63;
    const int w = tid >> 6;
    const int lr = lane & 15;
    const int q = lane >> 4;

    float bv[8];
#pragma unroll
    for (int nt = 0; nt < 8; ++nt) bv[nt] = bias[nt * 16 + lr];

    f32x4 acc[2][8];
#pragma unroll
    for (int mt = 0; mt < 2; ++mt)
#pragma unroll
        for (int nt = 0; nt < 8; ++nt) acc[mt][nt] = (f32x4){0.f, 0.f, 0.f, 0.f};

#pragma unroll
    for (int ks = 0; ks < 4; ++ks) {
        f16x8 af[2];
#pragma unroll
        for (int mt = 0; mt < 2; ++mt)
            af[mt] = *(const f16x8*)&As[(w * 32 + mt * 16 + lr) * 136 + ks * 32 + q * 8];
        f16x8 bfr[8];
#pragma unroll
        for (int nt = 0; nt < 8; ++nt)
            bfr[nt] = *(const f16x8*)&Bs[(nt * 16 + lr) * 136 + ks * 32 + q * 8];
#pragma unroll
        for (int mt = 0; mt < 2; ++mt)
#pragma unroll
            for (int nt = 0; nt < 8; ++nt)
                acc[mt][nt] = __builtin_amdgcn_mfma_f32_16x16x32_f16(
                    af[mt], bfr[nt], acc[mt][nt], 0, 0, 0);
    }

#pragma unroll
    for (int mt = 0; mt < 2; ++mt) {
        int rowbase = m0 + w * 32 + mt * 16 + q * 4;
#pragma unroll
        for (int r = 0; r < 4; ++r) {
            int n = rowbase + r;
            if (n < NN) {
                unsigned short* crow = O + (size_t)n * LDO + g * 128;
#pragma unroll
                for (int nt = 0; nt < 8; ++nt)
                    crow[nt * 16 + lr] = f2h(acc[mt][nt][r] + bv[nt]);
            }
        }
    }
}

// ---------------- CSR aggregate: ab[n][d] = fp16( sum in-edge O[ebase+d] ) -------------
// 1 wave = 2 nodes; lane covers 4 dims (8B fp16x4 gathers). Carries deg*b_t via O's bias.
__global__ void k_aggregate(const unsigned short* __restrict__ O,
                            const int* __restrict__ rowp, const int* __restrict__ ebase,
                            unsigned short* __restrict__ ab) {
    int wv = (blockIdx.x * 256 + threadIdx.x) >> 6;
    int lane = threadIdx.x & 63;
    int n = wv * 2 + (lane >> 5);
    if (n >= NN) return;
    int d4 = (lane & 31) * 4;
    int beg = rowp[n], end = rowp[n + 1];
    float a0 = 0.f, a1 = 0.f, a2 = 0.f, a3 = 0.f;
    for (int i = beg; i < end; ++i) {
        int b = ebase[i];
        f16x4 v = *(const f16x4*)&O[b + d4];
        a0 += (float)v[0]; a1 += (float)v[1]; a2 += (float)v[2]; a3 += (float)v[3];
    }
    f16x4 r;
    r[0] = (_Float16)a0; r[1] = (_Float16)a1; r[2] = (_Float16)a2; r[3] = (_Float16)a3;
    *(f16x4*)&ab[n * OD + d4] = r;
}

// ---------------- GEMM_P: P[n, g*128+o] -----------------------------------------------
// g=0 (pr):  ab.Wi_r^T + hb.Wh_r^T + b_ih[r]+b_hh[r]   (2 stages)
// g=1 (pz):  ab.Wi_z^T + hb.Wh_z^T + b_ih[z]+b_hh[z]   (2 stages)
// g=2 (pin): ab.Wi_n^T + b_ih[n]                        (1 stage)
// g=3 (phn): hb.Wh_n^T + b_hh[n]                        (1 stage)
// Each stage = proven single K=128 LDS chunk. Same XCD swizzle as k_gemm_a.
__global__ __launch_bounds__(256) void k_gemm_p(
    const unsigned short* __restrict__ ab, const unsigned short* __restrict__ hb,
    const unsigned short* __restrict__ Wib, const unsigned short* __restrict__ Whb,
    const float* __restrict__ b_ih, const float* __restrict__ b_hh,
    unsigned short* __restrict__ P) {
    __shared__ unsigned short As[128 * 136];
    __shared__ unsigned short Bs[128 * 136];

    const int b = blockIdx.x;
    const int xcd = b & 7, j = b >> 3;
    const int g = j & 3;
    const int tile = (j >> 2) * 8 + xcd;
    if (tile >= NT) return;
    const int m0 = tile * 128;
    const int tid = threadIdx.x;

    const unsigned short* Asrc[2];
    const unsigned short* Bsrc[2];
    int nst;
    if (g < 2) {
        Asrc[0] = ab; Bsrc[0] = Wib + (size_t)g * 16384;
        Asrc[1] = hb; Bsrc[1] = Whb + (size_t)g * 16384;
        nst = 2;
    } else if (g == 2) {
        Asrc[0] = ab; Bsrc[0] = Wib + (size_t)2 * 16384; nst = 1;
    } else {
        Asrc[0] = hb; Bsrc[0] = Whb + (size_t)2 * 16384; nst = 1;
    }

    const int lane = tid & 63;
    const int w = tid >> 6;
    const int lr = lane & 15;
    const int q = lane >> 4;

    f32x4 acc[2][8];
#pragma unroll
    for (int mt = 0; mt < 2; ++mt)
#pragma unroll
        for (int nt = 0; nt < 8; ++nt) acc[mt][nt] = (f32x4){0.f, 0.f, 0.f, 0.f};

    for (int st = 0; st < nst; ++st) {
        if (st) __syncthreads();   // previous stage's LDS reads done
        const uint4* A4 = (const uint4*)Asrc[st];
        const uint4* W4 = (const uint4*)Bsrc[st];
#pragma unroll
        for (int i = tid; i < 2048; i += 256) {
            int row = i >> 4, qq = i & 15;
            int n = m0 + row;
            uint4 va = (n < NN) ? A4[(size_t)n * 16 + qq] : make_uint4(0u, 0u, 0u, 0u);
            *(uint4*)&As[row * 136 + qq * 8] = va;
            *(uint4*)&Bs[row * 136 + qq * 8] = W4[(size_t)row * 16 + qq];
        }
        __syncthreads();
#pragma unroll
        for (int ks = 0; ks < 4; ++ks) {
            f16x8 af[2];
#pragma unroll
            for (int mt = 0; mt < 2; ++mt)
                af[mt] = *(const f16x8*)&As[(w * 32 + mt * 16 + lr) * 136 + ks * 32 + q * 8];
            f16x8 bfr[8];
#pragma unroll
            for (int nt = 0; nt < 8; ++nt)
                bfr[nt] = *(const f16x8*)&Bs[(nt * 16 + lr) * 136 + ks * 32 + q * 8];
#pragma unroll
            for (int mt = 0; mt < 2; ++mt)
#pragma unroll
                for (int nt = 0; nt < 8; ++nt)
                    acc[mt][nt] = __builtin_amdgcn_mfma_f32_16x16x32_f16(
                        af[mt], bfr[nt], acc[mt][nt], 0, 0, 0);
        }
    }

    // bias per gate group (L2-hot 512B tables)
    float bv[8];
#pragma unroll
    for (int nt = 0; nt < 8; ++nt) {
        int d = nt * 16 + lr;
        float v;
        if (g == 0)      v = b_ih[d] + b_hh[d];
        else if (g == 1) v = b_ih[128 + d] + b_hh[128 + d];
        else if (g == 2) v = b_ih[256 + d];
        else             v = b_hh[256 + d];
        bv[nt] = v;
    }

#pragma unroll
    for (int mt = 0; mt < 2; ++mt) {
        int rowbase = m0 + w * 32 + mt * 16 + q * 4;
#pragma unroll
        for (int r = 0; r < 4; ++r) {
            int n = rowbase + r;
            if (n < NN) {
                unsigned short* prow = P + (size_t)n * LDP + g * 128;
#pragma unroll
                for (int nt = 0; nt < 8; ++nt)
                    prow[nt * 16 + lr] = f2h(acc[mt][nt][r] + bv[nt]);
            }
        }
    }
}

// ---------------- pointwise GRU: P=[pr|pz|pin|phn] -> h, hb (4 dims/thread) -----------
__global__ void k_gru2(const unsigned short* __restrict__ P, float* __restrict__ h,
                       unsigned short* __restrict__ hb) {
    int i = blockIdx.x * 256 + threadIdx.x;
    if (i >= NN * 32) return;
    int n = i >> 5, d = (i & 31) * 4;
    const unsigned short* pr = P + (size_t)n * LDP;
    f16x4 vr = *(const f16x4*)&pr[d];
    f16x4 vz = *(const f16x4*)&pr[128 + d];
    f16x4 vi = *(const f16x4*)&pr[256 + d];
    f16x4 vh = *(const f16x4*)&pr[384 + d];
    float4 hv = *(const float4*)&h[(size_t)n * OD + d];
    float nh[4];
    float hvv[4] = {hv.x, hv.y, hv.z, hv.w};
#pragma unroll
    for (int jj = 0; jj < 4; ++jj) {
        float r = sigf((float)vr[jj]);
        float z = sigf((float)vz[jj]);
        float ng = tanhf((float)vi[jj] + r * (float)vh[jj]);
        nh[jj] = (1.f - z) * ng + z * hvv[jj];
    }
    *(float4*)&h[(size_t)n * OD + d] = make_float4(nh[0], nh[1], nh[2], nh[3]);
    f16x4 hb4;
    hb4[0] = (_Float16)nh[0]; hb4[1] = (_Float16)nh[1];
    hb4[2] = (_Float16)nh[2]; hb4[3] = (_Float16)nh[3];
    *(f16x4*)&hb[(size_t)n * OD + d] = hb4;
}

// ---------------- graph readout: register acc over graph-sorted node list --------------
__global__ void k_readout(const float* __restrict__ h, const float* __restrict__ nf,
                          const int* __restrict__ nlist, const int* __restrict__ growp,
                          float* __restrict__ partial) {
    int g = blockIdx.x >> 3, c = blockIdx.x & (RC - 1);
    int d = threadIdx.x;
    int s = growp[g], e = growp[g + 1], len = e - s;
    int i0 = s + (int)((long long)len * c / RC);
    int i1 = s + (int)((long long)len * (c + 1) / RC);
    float acc = 0.f;
    for (int i = i0; i < i1; ++i) {
        int n = nlist[i];
        acc += (d < OD) ? h[(size_t)n * OD + d] : nf[(size_t)n * IND + (d - OD)];
    }
    partial[(size_t)blockIdx.x * 192 + d] = acc;
}

__global__ void k_reduce(const float* __restrict__ partial, float* __restrict__ feats) {
    int i = blockIdx.x * 256 + threadIdx.x;
    if (i >= NG * 192) return;
    int g = i / 192, d = i % 192;
    float s = 0.f;
    for (int c = 0; c < RC; ++c) s += partial[(size_t)(g * RC + c) * 192 + d];
    feats[i] = s;
}

__global__ void k_final(const float* __restrict__ feats, const float* __restrict__ W_cls,
                        const float* __restrict__ b_cls, float* __restrict__ out) {
    int g = threadIdx.x;
    if (g >= NG) return;
    float acc = b_cls[0];
    for (int d = 0; d < 192; ++d) acc += feats[g * 192 + d] * W_cls[d];
    out[g] = 1.f / (1.f + __expf(-acc));
}

extern "C" void kernel_launch(void* const* d_in, const int* in_sizes, int n_in,
                              void* d_out, int out_size, void* d_ws, size_t ws_size,
                              hipStream_t stream) {
    const float* nf    = (const float*)d_in[0];
    const int*   src   = (const int*)d_in[1];
    const int*   dst   = (const int*)d_in[2];
    const int*   et    = (const int*)d_in[3];
    const int*   gid   = (const int*)d_in[4];
    const float* Ws    = (const float*)d_in[5];
    const float* bs    = (const float*)d_in[6];
    const float* W_ih  = (const float*)d_in[7];
    const float* W_hh  = (const float*)d_in[8];
    const float* b_ih  = (const float*)d_in[9];
    const float* b_hh  = (const float*)d_in[10];
    const float* W_cls = (const float*)d_in[11];
    const float* b_cls = (const float*)d_in[12];
    float* out = (float*)d_out;

    char* ws = (char*)d_ws;
    size_t off = 0;
    auto alloc = [&](size_t bytes) -> void* {
        off = (off + 255) & ~(size_t)255;
        void* p = ws + off;
        off += bytes;
        return p;
    };
    float*          h    = (float*)alloc((size_t)NN * OD * 4);            // 25.6 MB
    unsigned short* O    = (unsigned short*)alloc((size_t)NN * LDO * 2);  // 51.2 MB
    unsigned short* P    = (unsigned short*)alloc((size_t)NN * LDP * 2);  // 51.2 MB
    unsigned short* hb   = (unsigned short*)alloc((size_t)NN * OD * 2);   // 12.8 MB
    unsigned short* ab   = (unsigned short*)alloc((size_t)NN * OD * 2);   // 12.8 MB
    unsigned short* wall = (unsigned short*)alloc((size_t)10 * 16384 * 2);
    int*   deg    = (int*)alloc((size_t)NN * 4);
    int*   rowp   = (int*)alloc((size_t)(NN + 1) * 4);
    int*   cursor = (int*)alloc((size_t)NN * 4);
    int*   ebase  = (int*)alloc((size_t)NE * 4);
    int*   bsum   = (int*)alloc(64 * 4);
    int*   gdeg   = (int*)alloc(NG * 4);
    int*   growp  = (int*)alloc((NG + 1) * 4);
    int*   gcur   = (int*)alloc(NG * 4);
    int*   nlist  = (int*)alloc((size_t)NN * 4);
    float* feats  = (float*)alloc((size_t)NG * 192 * 4);
    (void)ws_size; (void)in_sizes; (void)n_in; (void)out_size;

    unsigned short* Wsb = wall;                 // 4 x 16384
    unsigned short* Wib = wall + 4 * 16384;     // 3 x 16384
    unsigned short* Whb = wall + 7 * 16384;     // 3 x 16384

    // readout partials alias the (dead-by-then) P buffer: 512*192*4 = 393 KB << 51 MB
    float* partial = (float*)P;

    hipMemsetAsync(deg, 0, (size_t)NN * 4, stream);
    hipMemsetAsync(gdeg, 0, NG * 4, stream);

    k_cvt_all<<<(10 * 16384 + 255) / 256, 256, 0, stream>>>(Ws, W_ih, W_hh, wall);
    k_init_h<<<(NN * OD + 255) / 256, 256, 0, stream>>>(nf, h, hb);
    k_count<<<(NE + 255) / 256, 256, 0, stream>>>(dst, deg);
    const int nb = (NN + 1023) / 1024;   // 49
    k_scan1<<<nb, 1024, 0, stream>>>(deg, rowp, bsum);
    k_scan2<<<1, 64, 0, stream>>>(bsum, nb);
    k_scan3<<<(NN + 255) / 256, 256, 0, stream>>>(deg, bsum, rowp, cursor);
    k_fill<<<(NE + 255) / 256, 256, 0, stream>>>(src, dst, et, cursor, ebase);

    k_gcount<<<nb, 1024, 0, stream>>>(gid, gdeg);
    k_gscan<<<1, NG, 0, stream>>>(gdeg, growp, gcur);
    k_gfill<<<nb, 1024, 0, stream>>>(gid, gcur, nlist);

    const int aggblk = (NN * 32 + 255) / 256;   // 2 nodes per wave
    for (int s = 0; s < 8; ++s) {
        k_gemm_a<<<SWGRID, 256, 0, stream>>>(hb, Wsb, bs, O);
        k_aggregate<<<aggblk, 256, 0, stream>>>(O, rowp, ebase, ab);
        k_gemm_p<<<SWGRID, 256, 0, stream>>>(ab, hb, Wib, Whb, b_ih, b_hh, P);
        k_gru2<<<(NN * 32 + 255) / 256, 256, 0, stream>>>(P, h, hb);
    }

    k_readout<<<NG * RC, 192, 0, stream>>>(h, nf, nlist, growp, partial);
    k_reduce<<<(NG * 192 + 255) / 256, 256, 0, stream>>>(partial, feats);
    k_final<<<1, 64, 0, stream>>>(feats, W_cls, b_cls, out);
}